// Round 17
// baseline (149.040 us; speedup 1.0000x reference)
//
#include <hip/hip_runtime.h>
#include <hip/hip_bf16.h>

#define BB 4
#define CC 256
#define CI 128
#define NN 4096

typedef _Float16 f16;
typedef __attribute__((ext_vector_type(8))) _Float16 f16x8;
typedef __attribute__((ext_vector_type(4))) _Float16 f16x4;
typedef __attribute__((ext_vector_type(4))) float f32x4;

#define MFMA(a,b,c) __builtin_amdgcn_mfma_f32_16x16x32_f16(a,b,c,0,0,0)
#define LDS3(p) ((__attribute__((address_space(3))) void*)(p))
#define GL1(p)  ((const __attribute__((address_space(1))) void*)(p))

// ---------------- K01: transpose+cast x -> xt, plus weight cast (fused k0) ----------------
__global__ __launch_bounds__(256) void k01_xpose(const float* x, f16* xt,
                                                 const float* tw, const float* pw,
                                                 const float* gw, const float* Ww, f16* wdst){
    int nt = blockIdx.x, ct = blockIdx.y, b = blockIdx.z;
    __shared__ float tile[64][65];
    int t = threadIdx.x;
    const float* src = x + ((size_t)(b*CC + ct*64))*NN + nt*64;
    #pragma unroll
    for (int k=0;k<16;k++){ int idx=t+k*256; int cl=idx>>6, nl=idx&63;
        tile[cl][nl]=src[(size_t)cl*NN + nl]; }
    __syncthreads();
    f16* dst = xt + ((size_t)(b*NN + nt*64))*CC + ct*64;
    #pragma unroll
    for (int k=0;k<16;k++){ int idx=t+k*256; int nl=idx>>6, cl=idx&63;
        dst[(size_t)nl*CC + cl] = (f16)tile[cl][nl]; }
    if (t < 128){
        int blkId = blockIdx.x + 64*(blockIdx.y + 4*blockIdx.z);
        int i = blkId*128 + t;
        int j = i & 32767; int sel = i >> 15;
        const float* s = (sel==0)? tw : (sel==1)? pw : (sel==2)? gw : Ww;
        wdst[i] = (f16)s[j];
    }
}

// ---------------- K2: merged theta/phi/g projections, 512 blocks ----------------
__global__ __launch_bounds__(256) void k2_all(const f16* xt, const f16* thw, const f16* phw,
                                              const f16* gwh, const float* thb, const float* phb,
                                              const float* gb, f16* th, f16* ph, f16* gt2){
    int b = blockIdx.y; int xx = blockIdx.x;
    int wv = threadIdx.x>>6, lane = threadIdx.x&63, q=lane>>4, cc=lane&15;
    if (xx < 64){
        int mat = xx>>5; int ntile = xx&31;
        int n0 = ntile*128 + wv*32;
        f16x8 aq[2][8];
        #pragma unroll
        for (int ns=0;ns<2;ns++){
            const f16* ap = xt + ((size_t)(b*NN + n0 + ns*16 + cc))*CC + q*8;
            #pragma unroll
            for (int kk=0;kk<8;kk++) aq[ns][kk] = *(const f16x8*)(ap + kk*32);
        }
        const f16* w   = mat? phw : thw;
        const float* bias = mat? phb : thb;
        f16* o = mat? ph : th;
        #pragma unroll 2
        for (int os=0;os<8;os++){
            f32x4 acc0={0,0,0,0}, acc1={0,0,0,0};
            const f16* wp = w + ((size_t)(os*16 + cc))*CC + q*8;
            #pragma unroll
            for (int kk=0;kk<8;kk++){
                f16x8 bf = *(const f16x8*)(wp + kk*32);
                acc0 = MFMA(aq[0][kk], bf, acc0);
                acc1 = MFMA(aq[1][kk], bf, acc1);
            }
            float bv = bias[os*16+cc];
            #pragma unroll
            for (int r=0;r<4;r++){
                o[((size_t)(b*NN + n0      + 4*q + r))*CI + os*16 + cc] = (f16)(acc0[r] + bv);
                o[((size_t)(b*NN + n0 + 16 + 4*q + r))*CI + os*16 + cc] = (f16)(acc1[r] + bv);
            }
        }
    } else {
        int mt = xx - 64;
        f16x8 ag[2][8];
        #pragma unroll
        for (int os=0;os<2;os++){
            const f16* ap = gwh + ((size_t)(wv*32 + os*16 + cc))*CC + q*8;
            #pragma unroll
            for (int kk=0;kk<8;kk++) ag[os][kk] = *(const f16x8*)(ap + kk*32);
        }
        f32x4 acc[2][4];
        #pragma unroll
        for (int os=0;os<2;os++){
            #pragma unroll
            for (int ms=0;ms<4;ms++) acc[os][ms]=(f32x4){0,0,0,0};
        }
        #pragma unroll 2
        for (int kk=0;kk<8;kk++){
            #pragma unroll
            for (int ms=0;ms<4;ms++){
                f16x8 bf = *(const f16x8*)(xt + ((size_t)(b*NN + mt*64 + ms*16 + cc))*CC + kk*32 + q*8);
                acc[0][ms]=MFMA(ag[0][kk],bf,acc[0][ms]);
                acc[1][ms]=MFMA(ag[1][kk],bf,acc[1][ms]);
            }
        }
        #pragma unroll
        for (int os=0;os<2;os++){
            #pragma unroll
            for (int r=0;r<4;r++){
                int orow = wv*32 + os*16 + 4*q + r;
                float bv = gb[orow];
                #pragma unroll
                for (int ms=0;ms<4;ms++){
                    int pos = (ms>>1)*32 + 8*(cc>>2) + 4*(ms&1) + (cc&3);
                    gt2[((size_t)(b*64 + mt))*8192 + orow*64 + pos] = (f16)(acc[os][ms][r] + bv);
                }
            }
        }
    }
}

// ---------------- K3 (nsp=4 fallback): round-16 verbatim, 64KB LDS, dbuf both ----------------
__global__ __launch_bounds__(256, 2) void k3_attn(const f16* th, const f16* ph, const f16* gt2,
                                                  f16* ypart, float* ml){
    int qt = blockIdx.x; int sp = blockIdx.y; int b = blockIdx.z;
    int wv=threadIdx.x>>6, lane=threadIdx.x&63, q=lane>>4, cc=lane&15;
    int qrow0 = qt*128 + wv*32;
    int kv0 = sp*1024;
    int sw  = cc<<4;
    int rsw = (cc&7)<<4;

    __shared__ __align__(16) char ldsb[65536];
    char* phL = ldsb;
    char* gtL = ldsb + 32768;

    f16x8 aq[2][4];
    #pragma unroll
    for (int rb=0;rb<2;rb++){
        const f16* thp = th + ((size_t)(b*NN + qrow0 + rb*16 + cc))*CI + q*8;
        #pragma unroll
        for (int kk=0;kk<4;kk++) aq[rb][kk] = *(const f16x8*)(thp + kk*32);
    }
    const char* phg = (const char*)(ph + (size_t)b*NN*CI);
    const char* gtg = (const char*)gt2 + (size_t)b*64*16384;

    f32x4 yacc[2][8];
    #pragma unroll
    for (int rb=0;rb<2;rb++)
        #pragma unroll
        for (int os=0;os<8;os++) yacc[rb][os]=(f32x4){0,0,0,0};
    float m_run0=-1e30f, m_run1=-1e30f, l_run0=0.f, l_run1=0.f;

    auto STAGE = [&](int tt, int bb){
        int key0 = kv0 + tt*64;
        int mt  = key0 >> 6;
        char* pbase = phL + bb*16384 + wv*4096;
        char* gbase = gtL + bb*16384 + wv*4096;
        #pragma unroll
        for (int ch=0; ch<4; ch++){
            int prow = wv*16 + ch*4 + (lane>>4);
            const char* ps = phg + (size_t)(key0 + prow)*256 + (((lane&15)*16) ^ ((prow&15)<<4));
            __builtin_amdgcn_global_load_lds(GL1(ps), LDS3(pbase + ch*1024), 16, 0, 0);
            int gf = wv*4096 + ch*1024 + lane*16;
            int grow = gf>>7, gcol = gf&127;
            int scol = gcol ^ ((grow&7)<<4);
            const char* gs = gtg + (size_t)mt*16384 + grow*128 + scol;
            __builtin_amdgcn_global_load_lds(GL1(gs), LDS3(gbase + ch*1024), 16, 0, 0);
        }
    };

    STAGE(0, 0);
    __syncthreads();
    int cur = 0;
    #pragma unroll 1
    for (int it=0; it<16; ++it){
        if (it < 15) STAGE(it+1, cur^1);
        const char* pt  = phL + cur*16384;
        const char* gtt = gtL + cur*16384;
        f32x4 fa[2][4];
        #pragma unroll
        for (int j=0;j<4;j++){
            f16x8 pf[4];
            #pragma unroll
            for (int kk=0;kk<4;kk++)
                pf[kk] = *(const f16x8*)(pt + (j*16+cc)*256 + ((kk*64 + q*16) ^ sw));
            fa[0][j]=(f32x4){0,0,0,0}; fa[1][j]=(f32x4){0,0,0,0};
            #pragma unroll
            for (int kk=0;kk<4;kk++){
                fa[0][j]=MFMA(pf[kk], aq[0][kk], fa[0][j]);
                fa[1][j]=MFMA(pf[kk], aq[1][kk], fa[1][j]);
            }
        }
        float pm0 = fmaxf(fmaxf(fmaxf(fa[0][0][0],fa[0][0][1]),fmaxf(fa[0][0][2],fa[0][0][3])),
                          fmaxf(fmaxf(fa[0][1][0],fa[0][1][1]),fmaxf(fa[0][1][2],fa[0][1][3])));
        pm0 = fmaxf(pm0, fmaxf(fmaxf(fa[0][2][0],fa[0][2][1]),fmaxf(fa[0][2][2],fa[0][2][3])));
        pm0 = fmaxf(pm0, fmaxf(fmaxf(fa[0][3][0],fa[0][3][1]),fmaxf(fa[0][3][2],fa[0][3][3])));
        float pm1 = fmaxf(fmaxf(fmaxf(fa[1][0][0],fa[1][0][1]),fmaxf(fa[1][0][2],fa[1][0][3])),
                          fmaxf(fmaxf(fa[1][1][0],fa[1][1][1]),fmaxf(fa[1][1][2],fa[1][1][3])));
        pm1 = fmaxf(pm1, fmaxf(fmaxf(fa[1][2][0],fa[1][2][1]),fmaxf(fa[1][2][2],fa[1][2][3])));
        pm1 = fmaxf(pm1, fmaxf(fmaxf(fa[1][3][0],fa[1][3][1]),fmaxf(fa[1][3][2],fa[1][3][3])));
        if (__any(fmaxf(pm0 - m_run0, pm1 - m_run1) > 3.f)){
            float mx0 = pm0;
            mx0 = fmaxf(mx0, __shfl_xor(mx0,16));
            mx0 = fmaxf(mx0, __shfl_xor(mx0,32));
            float mx1 = pm1;
            mx1 = fmaxf(mx1, __shfl_xor(mx1,16));
            mx1 = fmaxf(mx1, __shfl_xor(mx1,32));
            float nm0 = fmaxf(m_run0, mx0), nm1 = fmaxf(m_run1, mx1);
            float co0 = __expf(m_run0 - nm0), co1 = __expf(m_run1 - nm1);
            m_run0 = nm0; m_run1 = nm1;
            l_run0 *= co0; l_run1 *= co1;
            #pragma unroll
            for (int os=0;os<8;os++){ yacc[0][os] *= co0; yacc[1][os] *= co1; }
        }
        #pragma unroll
        for (int j=0;j<4;j++){
            #pragma unroll
            for (int r=0;r<4;r++){
                fa[0][j][r] = __expf(fa[0][j][r]-m_run0);
                fa[1][j][r] = __expf(fa[1][j][r]-m_run1);
            }
        }
        l_run0 += ((fa[0][0][0]+fa[0][0][1]+fa[0][0][2]+fa[0][0][3])
                 + (fa[0][1][0]+fa[0][1][1]+fa[0][1][2]+fa[0][1][3]))
                + ((fa[0][2][0]+fa[0][2][1]+fa[0][2][2]+fa[0][2][3])
                 + (fa[0][3][0]+fa[0][3][1]+fa[0][3][2]+fa[0][3][3]));
        l_run1 += ((fa[1][0][0]+fa[1][0][1]+fa[1][0][2]+fa[1][0][3])
                 + (fa[1][1][0]+fa[1][1][1]+fa[1][1][2]+fa[1][1][3]))
                + ((fa[1][2][0]+fa[1][2][1]+fa[1][2][2]+fa[1][2][3])
                 + (fa[1][3][0]+fa[1][3][1]+fa[1][3][2]+fa[1][3][3]));
        f16x8 pb0h0, pb0h1, pb1h0, pb1h1;
        #pragma unroll
        for (int r=0;r<4;r++){
            pb0h0[r]=(f16)fa[0][0][r]; pb0h0[4+r]=(f16)fa[0][1][r];
            pb0h1[r]=(f16)fa[0][2][r]; pb0h1[4+r]=(f16)fa[0][3][r];
            pb1h0[r]=(f16)fa[1][0][r]; pb1h0[4+r]=(f16)fa[1][1][r];
            pb1h1[r]=(f16)fa[1][2][r]; pb1h1[4+r]=(f16)fa[1][3][r];
        }
        #pragma unroll
        for (int os=0;os<8;os++){
            int row = os*16 + cc;
            f16x8 ga0 = *(const f16x8*)(gtt + row*128 + (((0<<6)|(q<<4)) ^ rsw));
            f16x8 ga1 = *(const f16x8*)(gtt + row*128 + (((1<<6)|(q<<4)) ^ rsw));
            yacc[0][os] = MFMA(ga0, pb0h0, yacc[0][os]);
            yacc[1][os] = MFMA(ga0, pb1h0, yacc[1][os]);
            yacc[0][os] = MFMA(ga1, pb0h1, yacc[0][os]);
            yacc[1][os] = MFMA(ga1, pb1h1, yacc[1][os]);
        }
        __syncthreads();
        cur ^= 1;
    }
    float l0 = l_run0; l0 += __shfl_xor(l0,16); l0 += __shfl_xor(l0,32);
    float l1 = l_run1; l1 += __shfl_xor(l1,16); l1 += __shfl_xor(l1,32);
    float linv0 = 1.f/l0, linv1 = 1.f/l1;
    f16* yl = (f16*)(ldsb + wv*8192);
    #pragma unroll
    for (int os=0;os<8;os++){
        #pragma unroll
        for (int r=0;r<4;r++){
            int o = os*16 + 4*q + r;
            *(f16*)((char*)yl + cc*256      + ((o*2) ^ ((cc&7)<<4))) = (f16)(yacc[0][os][r]*linv0);
            *(f16*)((char*)yl + (16+cc)*256 + ((o*2) ^ ((cc&7)<<4))) = (f16)(yacc[1][os][r]*linv1);
        }
    }
    #pragma unroll
    for (int p=0;p<8;p++){
        int idx = p*512 + lane*8;
        int row = idx>>7, o0 = idx&127;
        f16x8 v = *(const f16x8*)((char*)yl + row*256 + ((o0*2) ^ ((row&7)<<4)));
        *(f16x8*)(ypart + ((size_t)((sp*4+b)*NN + qrow0 + row))*CI + o0) = v;
    }
    if (lane < 16){
        size_t row0 = (size_t)(sp*4+b)*NN + qrow0 + lane;
        ml[row0*2]        = m_run0;
        ml[row0*2+1]      = l0;
        ml[(row0+16)*2]   = m_run1;
        ml[(row0+16)*2+1] = l1;
    }
}

// ---------------- K3 (nsp=8): phi single-buffered, 48KB LDS, 3 blocks/CU ----------------
__global__ __launch_bounds__(256, 3) void k3_attn8(const f16* th, const f16* ph, const f16* gt2,
                                                   f16* ypart, float* ml){
    int qt = blockIdx.x;           // 32 q-tiles of 128 rows
    int sp = blockIdx.y;           // 8 key splits of 512 keys
    int b  = blockIdx.z;
    int wv=threadIdx.x>>6, lane=threadIdx.x&63, q=lane>>4, cc=lane&15;
    int qrow0 = qt*128 + wv*32;
    int kv0 = sp*512;
    int sw  = cc<<4;
    int rsw = (cc&7)<<4;

    __shared__ __align__(16) char ldsb[49152];
    char* phL = ldsb;                 // [16384] phi single buffer
    char* gtL = ldsb + 16384;         // [2][16384] gt dbuf

    f16x8 aq[2][4];
    #pragma unroll
    for (int rb=0;rb<2;rb++){
        const f16* thp = th + ((size_t)(b*NN + qrow0 + rb*16 + cc))*CI + q*8;
        #pragma unroll
        for (int kk=0;kk<4;kk++) aq[rb][kk] = *(const f16x8*)(thp + kk*32);
    }
    const char* phg = (const char*)(ph + (size_t)b*NN*CI);
    const char* gtg = (const char*)gt2 + (size_t)b*64*16384;

    f32x4 yacc[2][8];
    #pragma unroll
    for (int rb=0;rb<2;rb++)
        #pragma unroll
        for (int os=0;os<8;os++) yacc[rb][os]=(f32x4){0,0,0,0};
    float m_run0=-1e30f, m_run1=-1e30f, l_run0=0.f, l_run1=0.f;

    auto STAGE_PH = [&](int tt){
        int key0 = kv0 + tt*64;
        char* pbase = phL + wv*4096;
        #pragma unroll
        for (int ch=0; ch<4; ch++){
            int prow = wv*16 + ch*4 + (lane>>4);
            const char* ps = phg + (size_t)(key0 + prow)*256 + (((lane&15)*16) ^ ((prow&15)<<4));
            __builtin_amdgcn_global_load_lds(GL1(ps), LDS3(pbase + ch*1024), 16, 0, 0);
        }
    };
    auto STAGE_GT = [&](int tt, int bb){
        int key0 = kv0 + tt*64;
        int mt  = key0 >> 6;
        char* gbase = gtL + bb*16384 + wv*4096;
        #pragma unroll
        for (int ch=0; ch<4; ch++){
            int gf = wv*4096 + ch*1024 + lane*16;
            int grow = gf>>7, gcol = gf&127;
            int scol = gcol ^ ((grow&7)<<4);
            const char* gs = gtg + (size_t)mt*16384 + grow*128 + scol;
            __builtin_amdgcn_global_load_lds(GL1(gs), LDS3(gbase + ch*1024), 16, 0, 0);
        }
    };

    STAGE_PH(0);
    STAGE_GT(0, 0);
    __syncthreads();

    int cur = 0;
    #pragma unroll 1
    for (int it=0; it<8; ++it){
        // QK^T from the single phi buffer
        f32x4 fa[2][4];
        #pragma unroll
        for (int j=0;j<4;j++){
            f16x8 pf[4];
            #pragma unroll
            for (int kk=0;kk<4;kk++)
                pf[kk] = *(const f16x8*)(phL + (j*16+cc)*256 + ((kk*64 + q*16) ^ sw));
            fa[0][j]=(f32x4){0,0,0,0}; fa[1][j]=(f32x4){0,0,0,0};
            #pragma unroll
            for (int kk=0;kk<4;kk++){
                fa[0][j]=MFMA(pf[kk], aq[0][kk], fa[0][j]);
                fa[1][j]=MFMA(pf[kk], aq[1][kk], fa[1][j]);
            }
        }
        __syncthreads();   // barrier1: all waves done reading phi (no loads outstanding here)
        if (it < 7){
            STAGE_PH(it+1);            // restage phi in place; latency hides under softmax+PV
            STAGE_GT(it+1, cur^1);
        }
        // lazy-max softmax
        float pm0 = fmaxf(fmaxf(fmaxf(fa[0][0][0],fa[0][0][1]),fmaxf(fa[0][0][2],fa[0][0][3])),
                          fmaxf(fmaxf(fa[0][1][0],fa[0][1][1]),fmaxf(fa[0][1][2],fa[0][1][3])));
        pm0 = fmaxf(pm0, fmaxf(fmaxf(fa[0][2][0],fa[0][2][1]),fmaxf(fa[0][2][2],fa[0][2][3])));
        pm0 = fmaxf(pm0, fmaxf(fmaxf(fa[0][3][0],fa[0][3][1]),fmaxf(fa[0][3][2],fa[0][3][3])));
        float pm1 = fmaxf(fmaxf(fmaxf(fa[1][0][0],fa[1][0][1]),fmaxf(fa[1][0][2],fa[1][0][3])),
                          fmaxf(fmaxf(fa[1][1][0],fa[1][1][1]),fmaxf(fa[1][1][2],fa[1][1][3])));
        pm1 = fmaxf(pm1, fmaxf(fmaxf(fa[1][2][0],fa[1][2][1]),fmaxf(fa[1][2][2],fa[1][2][3])));
        pm1 = fmaxf(pm1, fmaxf(fmaxf(fa[1][3][0],fa[1][3][1]),fmaxf(fa[1][3][2],fa[1][3][3])));
        if (__any(fmaxf(pm0 - m_run0, pm1 - m_run1) > 3.f)){
            float mx0 = pm0;
            mx0 = fmaxf(mx0, __shfl_xor(mx0,16));
            mx0 = fmaxf(mx0, __shfl_xor(mx0,32));
            float mx1 = pm1;
            mx1 = fmaxf(mx1, __shfl_xor(mx1,16));
            mx1 = fmaxf(mx1, __shfl_xor(mx1,32));
            float nm0 = fmaxf(m_run0, mx0), nm1 = fmaxf(m_run1, mx1);
            float co0 = __expf(m_run0 - nm0), co1 = __expf(m_run1 - nm1);
            m_run0 = nm0; m_run1 = nm1;
            l_run0 *= co0; l_run1 *= co1;
            #pragma unroll
            for (int os=0;os<8;os++){ yacc[0][os] *= co0; yacc[1][os] *= co1; }
        }
        #pragma unroll
        for (int j=0;j<4;j++){
            #pragma unroll
            for (int r=0;r<4;r++){
                fa[0][j][r] = __expf(fa[0][j][r]-m_run0);
                fa[1][j][r] = __expf(fa[1][j][r]-m_run1);
            }
        }
        l_run0 += ((fa[0][0][0]+fa[0][0][1]+fa[0][0][2]+fa[0][0][3])
                 + (fa[0][1][0]+fa[0][1][1]+fa[0][1][2]+fa[0][1][3]))
                + ((fa[0][2][0]+fa[0][2][1]+fa[0][2][2]+fa[0][2][3])
                 + (fa[0][3][0]+fa[0][3][1]+fa[0][3][2]+fa[0][3][3]));
        l_run1 += ((fa[1][0][0]+fa[1][0][1]+fa[1][0][2]+fa[1][0][3])
                 + (fa[1][1][0]+fa[1][1][1]+fa[1][1][2]+fa[1][1][3]))
                + ((fa[1][2][0]+fa[1][2][1]+fa[1][2][2]+fa[1][2][3])
                 + (fa[1][3][0]+fa[1][3][1]+fa[1][3][2]+fa[1][3][3]));
        f16x8 pb0h0, pb0h1, pb1h0, pb1h1;
        #pragma unroll
        for (int r=0;r<4;r++){
            pb0h0[r]=(f16)fa[0][0][r]; pb0h0[4+r]=(f16)fa[0][1][r];
            pb0h1[r]=(f16)fa[0][2][r]; pb0h1[4+r]=(f16)fa[0][3][r];
            pb1h0[r]=(f16)fa[1][0][r]; pb1h0[4+r]=(f16)fa[1][1][r];
            pb1h1[r]=(f16)fa[1][2][r]; pb1h1[4+r]=(f16)fa[1][3][r];
        }
        const char* gtt = gtL + cur*16384;
        #pragma unroll
        for (int os=0;os<8;os++){
            int row = os*16 + cc;
            f16x8 ga0 = *(const f16x8*)(gtt + row*128 + (((0<<6)|(q<<4)) ^ rsw));
            f16x8 ga1 = *(const f16x8*)(gtt + row*128 + (((1<<6)|(q<<4)) ^ rsw));
            yacc[0][os] = MFMA(ga0, pb0h0, yacc[0][os]);
            yacc[1][os] = MFMA(ga0, pb1h0, yacc[1][os]);
            yacc[0][os] = MFMA(ga1, pb0h1, yacc[0][os]);
            yacc[1][os] = MFMA(ga1, pb1h1, yacc[1][os]);
        }
        __syncthreads();   // barrier2: drains phi+gt staging; gt[cur] reads done
        cur ^= 1;
    }
    float l0 = l_run0; l0 += __shfl_xor(l0,16); l0 += __shfl_xor(l0,32);
    float l1 = l_run1; l1 += __shfl_xor(l1,16); l1 += __shfl_xor(l1,32);
    float linv0 = 1.f/l0, linv1 = 1.f/l1;
    f16* yl = (f16*)(ldsb + wv*8192);
    #pragma unroll
    for (int os=0;os<8;os++){
        #pragma unroll
        for (int r=0;r<4;r++){
            int o = os*16 + 4*q + r;
            *(f16*)((char*)yl + cc*256      + ((o*2) ^ ((cc&7)<<4))) = (f16)(yacc[0][os][r]*linv0);
            *(f16*)((char*)yl + (16+cc)*256 + ((o*2) ^ ((cc&7)<<4))) = (f16)(yacc[1][os][r]*linv1);
        }
    }
    #pragma unroll
    for (int p=0;p<8;p++){
        int idx = p*512 + lane*8;
        int row = idx>>7, o0 = idx&127;
        f16x8 v = *(const f16x8*)((char*)yl + row*256 + ((o0*2) ^ ((row&7)<<4)));
        *(f16x8*)(ypart + ((size_t)((sp*4+b)*NN + qrow0 + row))*CI + o0) = v;
    }
    if (lane < 16){
        size_t row0 = (size_t)(sp*4+b)*NN + qrow0 + lane;
        ml[row0*2]        = m_run0;
        ml[row0*2+1]      = l0;
        ml[(row0+16)*2]   = m_run1;
        ml[(row0+16)*2+1] = l1;
    }
}

// ---------------- K3c: fused combine + Gram/mean stats (MFMA), nsp-generic ----------------
__global__ __launch_bounds__(256) void k3c(const f16* ypart, const float* ml,
                                           f16* y, float* part, float* mupart, int nsp){
    int blk = blockIdx.x; int t = threadIdx.x;     // 256 blocks
    int rloc = t>>2;
    int row  = blk*64 + rloc;
    int b = row>>12, n = row & 4095;
    int o0 = (t&3)*32;
    __shared__ __align__(16) f16 ldsT[128*64];
    float M = -1e30f;
    #pragma unroll 1
    for (int s=0;s<nsp;s++) M = fmaxf(M, ml[((size_t)(s*4+b)*NN + n)*2]);
    float L = 0.f;
    #pragma unroll 1
    for (int s=0;s<nsp;s++){
        size_t r2 = ((size_t)(s*4+b)*NN + n)*2;
        L += ml[r2+1]*__expf(ml[r2]-M);
    }
    float inv = 1.f/L;
    float acc[32];
    #pragma unroll
    for (int j=0;j<32;j++) acc[j]=0.f;
    #pragma unroll 1
    for (int s=0;s<nsp;s++){
        size_t r2 = ((size_t)(s*4+b)*NN + n)*2;
        float w = ml[r2+1]*__expf(ml[r2]-M)*inv;
        const f16* src = ypart + ((size_t)(s*4+b)*NN + n)*CI + o0;
        #pragma unroll
        for (int v=0;v<4;v++){
            f16x8 vv = *(const f16x8*)(src + v*8);
            #pragma unroll
            for (int e=0;e<8;e++) acc[v*8+e] += w*(float)vv[e];
        }
    }
    f16* yo = y + (size_t)row*CI + o0;
    #pragma unroll
    for (int v=0;v<4;v++){
        f16x8 ov;
        #pragma unroll
        for (int e=0;e<8;e++) ov[e] = (f16)acc[v*8+e];
        *(f16x8*)(yo + v*8) = ov;
        #pragma unroll
        for (int e=0;e<8;e++){
            int o = o0 + v*8 + e;
            ldsT[o*64 + (rloc ^ ((o&7)<<3))] = ov[e];
        }
    }
    __syncthreads();
    int wv=t>>6, lane=t&63, q=lane>>4, cc=lane&15;
    f32x4 gacc[2][8];
    #pragma unroll
    for (int a=0;a<2;a++)
        #pragma unroll
        for (int c2=0;c2<8;c2++) gacc[a][c2]=(f32x4){0,0,0,0};
    f16x8 af[2][2];
    #pragma unroll
    for (int o1t=0;o1t<2;o1t++){
        int o1 = (wv*2+o1t)*16+cc;
        #pragma unroll
        for (int kk=0;kk<2;kk++)
            af[o1t][kk] = *(const f16x8*)(ldsT + o1*64 + ((kk*32+q*8) ^ ((o1&7)<<3)));
    }
    #pragma unroll 1
    for (int o2t=0;o2t<8;o2t++){
        int o2 = o2t*16+cc;
        #pragma unroll
        for (int kk=0;kk<2;kk++){
            f16x8 bf = *(const f16x8*)(ldsT + o2*64 + ((kk*32+q*8) ^ ((o2&7)<<3)));
            gacc[0][o2t] = MFMA(af[0][kk], bf, gacc[0][o2t]);
            gacc[1][o2t] = MFMA(af[1][kk], bf, gacc[1][o2t]);
        }
    }
    float* pb = part + (size_t)blk*16384;
    #pragma unroll
    for (int o1t=0;o1t<2;o1t++){
        #pragma unroll
        for (int o2t=0;o2t<8;o2t++){
            #pragma unroll
            for (int r=0;r<4;r++)
                pb[((wv*2+o1t)*16+4*q+r)*128 + o2t*16+cc] = gacc[o1t][o2t][r];
        }
    }
    if (t<128){
        float sm=0.f;
        #pragma unroll
        for (int v=0;v<8;v++){
            f16x8 vv = *(const f16x8*)(ldsT + t*64 + ((v*8) ^ ((t&7)<<3)));
            #pragma unroll
            for (int e=0;e<8;e++) sm += (float)vv[e];
        }
        mupart[blk*128 + t] = sm;
    }
}

// ---------------- K4b: chunked reduce of partials -> atomicAdd into S (pre-zeroed) ----------------
__global__ __launch_bounds__(256) void k4b_red(const float* part, const float* mupart, float* S){
    int pc = blockIdx.y;
    int t = threadIdx.x;
    if (blockIdx.x < 64){
        int i = blockIdx.x*256 + t;
        float s=0.f;
        #pragma unroll 1
        for (int p=pc*32; p<pc*32+32; p++) s += part[(size_t)p*16384 + i];
        atomicAdd(&S[i], s);
    } else if (t < 128){
        float s=0.f;
        #pragma unroll 1
        for (int p=pc*32; p<pc*32+32; p++) s += mupart[p*128 + t];
        atomicAdd(&S[16384+t], s);
    }
}

// ---------------- K4c: BN coefficients A[ch], B4[ch] ----------------
__global__ __launch_bounds__(128) void k4c_coef(const float* S, const float* Ww, const float* Wb,
                                                const float* gamma, const float* beta,
                                                const float* scale, float* AB){
    int ch = blockIdx.x; int t = threadIdx.x;
    const float* w = Ww + ch*CI;
    float tmp=0.f;
    const float* Srow = S + t*CI;
    #pragma unroll 1
    for (int o2=0;o2<CI;o2++) tmp += Srow[o2]*w[o2];
    float v  = w[t]*tmp;
    float mc = w[t]*S[16384 + t];
    #pragma unroll
    for (int s=1;s<64;s<<=1){ v += __shfl_xor(v,s); mc += __shfl_xor(mc,s); }
    __shared__ float red[4];
    if ((t&63)==0){ red[(t>>6)*2]=v; red[(t>>6)*2+1]=mc; }
    __syncthreads();
    if (t==0){
        float wSw = red[0]+red[2];
        float wmu = red[1]+red[3];
        const float M = 16384.f;
        float meanwy = wmu/M + Wb[ch];
        float var = wSw/M - (wmu/M)*(wmu/M);
        float inv = rsqrtf(var + 1e-5f);
        float sc = scale[0];
        float A  = sc*gamma[ch]*inv;
        float B3 = sc*(beta[ch] - meanwy*inv*gamma[ch]);
        AB[ch]     = A;
        AB[256+ch] = B3 + A*Wb[ch];
    }
}

// ---------------- K5: fused W-conv + BN + scale + residual, 512 blocks ----------------
__global__ __launch_bounds__(256) void k5_out(const f16* Wwh, const f16* y, const float* x,
                                              const float* AB, float* out){
    int ntile = blockIdx.x;
    int cht   = blockIdx.y;
    int b     = blockIdx.z;
    int wv=threadIdx.x>>6, lane=threadIdx.x&63, q=lane>>4, cc=lane&15;
    int ch0 = cht*64 + wv*16;
    f16x8 aw[4];
    const f16* wp = Wwh + ((size_t)(ch0+cc))*CI + q*8;
    #pragma unroll
    for (int kk=0;kk<4;kk++) aw[kk]=*(const f16x8*)(wp+kk*32);
    float Ar[4], Br[4];
    #pragma unroll
    for (int r=0;r<4;r++){ Ar[r]=AB[ch0+4*q+r]; Br[r]=AB[256+ch0+4*q+r]; }
    #pragma unroll 2
    for (int ns=0;ns<8;ns++){
        int n0 = ntile*128 + ns*16;
        f32x4 acc={0,0,0,0};
        const f16* yp = y + ((size_t)(b*NN + n0 + cc))*CI + q*8;
        #pragma unroll
        for (int kk=0;kk<4;kk++) acc = MFMA(aw[kk], *(const f16x8*)(yp+kk*32), acc);
        #pragma unroll
        for (int r=0;r<4;r++){
            size_t addr = ((size_t)(b*CC + ch0 + 4*q + r))*NN + n0 + cc;
            out[addr] = x[addr] + Ar[r]*acc[r] + Br[r];
        }
    }
}

extern "C" void kernel_launch(void* const* d_in, const int* in_sizes, int n_in,
                              void* d_out, int out_size, void* d_ws, size_t ws_size,
                              hipStream_t stream){
    const float* x    = (const float*)d_in[0];
    const float* g_w  = (const float*)d_in[1];
    const float* g_b  = (const float*)d_in[2];
    const float* th_w = (const float*)d_in[3];
    const float* th_b = (const float*)d_in[4];
    const float* ph_w = (const float*)d_in[5];
    const float* ph_b = (const float*)d_in[6];
    const float* W_w  = (const float*)d_in[7];
    const float* W_b  = (const float*)d_in[8];
    const float* bg   = (const float*)d_in[9];
    const float* bb   = (const float*)d_in[10];
    const float* sc   = (const float*)d_in[11];

    char* ws = (char*)d_ws;
    const size_t NEED8 = 60300000ull;
    int nsp = (ws_size >= NEED8) ? 8 : 4;

    f16 *xt, *th, *ph, *gt2, *y, *wh, *ypart;
    float *ml, *part, *mupart, *S, *AB;
    if (nsp == 8){
        xt    = (f16*)(ws);                       // 0        (8.4M, dead after k2)
        th    = (f16*)(ws + 8388608);
        ph    = (f16*)(ws + 12582912);
        gt2   = (f16*)(ws + 16777216);
        wh    = (f16*)(ws + 20971520);            // 256 KB
        ml    = (float*)(ws + 21233664);          // 1.05 MB (8*4*4096*2 f32)
        y     = (f16*)(ws + 22282240);            // 4.2 MB
        ypart = (f16*)(ws + 26476544);            // 33.55 MB
        S     = (float*)(ws + 60030976);          // 66 KB
        AB    = (float*)(ws + 60097024);          // 2 KB
        mupart= (float*)(ws + 60099072);          // 128 KB
        part  = (float*)ws;                       // 16.8M overlay on xt+th (dead after k3)
    } else {
        xt    = (f16*)(ws);
        th    = (f16*)(ws + 8388608);
        ph    = (f16*)(ws + 12582912);
        gt2   = (f16*)(ws + 16777216);
        y     = (f16*)(ws + 20971520);
        wh    = (f16*)(ws + 25165824);
        ml    = (float*)(ws + 25427968);
        ypart = (f16*)(ws + 25952256);
        mupart= (float*)(ws + 42729472);
        part  = (float*)ws;
        S     = (float*)(ws + 42860544);
        AB    = (float*)(ws + 42926592);
    }
    f16* th_wh = wh;
    f16* ph_wh = wh + 32768;
    f16* g_wh  = wh + 65536;
    f16* Ww_h  = wh + 98304;

    hipMemsetAsync(S, 0, 16512*sizeof(float), stream);
    hipLaunchKernelGGL(k01_xpose, dim3(64,4,4), dim3(256), 0, stream, x, xt, th_w, ph_w, g_w, W_w, wh);
    hipLaunchKernelGGL(k2_all,   dim3(128,4),   dim3(256), 0, stream, xt, th_wh, ph_wh, g_wh,
                       th_b, ph_b, g_b, th, ph, gt2);
    if (nsp == 8)
        hipLaunchKernelGGL(k3_attn8, dim3(32,8,4), dim3(256), 0, stream, th, ph, gt2, ypart, ml);
    else
        hipLaunchKernelGGL(k3_attn,  dim3(32,4,4), dim3(256), 0, stream, th, ph, gt2, ypart, ml);
    hipLaunchKernelGGL(k3c,      dim3(256),     dim3(256), 0, stream, ypart, ml, y, part, mupart, nsp);
    hipLaunchKernelGGL(k4b_red,  dim3(65,8),    dim3(256), 0, stream, part, mupart, S);
    hipLaunchKernelGGL(k4c_coef, dim3(256),     dim3(128), 0, stream, S, W_w, W_b, bg, bb, sc, AB);
    hipLaunchKernelGGL(k5_out,   dim3(32,4,4),  dim3(256), 0, stream, Ww_h, y, x, AB, (float*)d_out);
}

// Round 18
// 135.807 us; speedup vs baseline: 1.0974x; 1.0974x over previous
//
#include <hip/hip_runtime.h>
#include <hip/hip_bf16.h>

#define BB 4
#define CC 256
#define CI 128
#define NN 4096

typedef _Float16 f16;
typedef __attribute__((ext_vector_type(8))) _Float16 f16x8;
typedef __attribute__((ext_vector_type(4))) _Float16 f16x4;
typedef __attribute__((ext_vector_type(4))) float f32x4;

#define MFMA(a,b,c) __builtin_amdgcn_mfma_f32_16x16x32_f16(a,b,c,0,0,0)
#define LDS3(p) ((__attribute__((address_space(3))) void*)(p))
#define GL1(p)  ((const __attribute__((address_space(1))) void*)(p))

// ---------------- K01: transpose+cast x -> xt, plus weight cast (fused k0) ----------------
__global__ __launch_bounds__(256) void k01_xpose(const float* x, f16* xt,
                                                 const float* tw, const float* pw,
                                                 const float* gw, const float* Ww, f16* wdst){
    int nt = blockIdx.x, ct = blockIdx.y, b = blockIdx.z;
    __shared__ float tile[64][65];
    int t = threadIdx.x;
    const float* src = x + ((size_t)(b*CC + ct*64))*NN + nt*64;
    #pragma unroll
    for (int k=0;k<16;k++){ int idx=t+k*256; int cl=idx>>6, nl=idx&63;
        tile[cl][nl]=src[(size_t)cl*NN + nl]; }
    __syncthreads();
    f16* dst = xt + ((size_t)(b*NN + nt*64))*CC + ct*64;
    #pragma unroll
    for (int k=0;k<16;k++){ int idx=t+k*256; int nl=idx>>6, cl=idx&63;
        dst[(size_t)nl*CC + cl] = (f16)tile[cl][nl]; }
    // fused weight cast: 1024 blocks x 128 elements = 131072
    if (t < 128){
        int blkId = blockIdx.x + 64*(blockIdx.y + 4*blockIdx.z);
        int i = blkId*128 + t;
        int j = i & 32767; int sel = i >> 15;
        const float* s = (sel==0)? tw : (sel==1)? pw : (sel==2)? gw : Ww;
        wdst[i] = (f16)s[j];
    }
}

// ---------------- K2: merged theta/phi/g projections, 512 blocks ----------------
// g output gt2[b][mt][o][64] with keys PERMUTED within each 32-half:
// key K=16j+4a+r stored at p = 8a+4j+r  (so k3's PV A-frag is one b128).
__global__ __launch_bounds__(256) void k2_all(const f16* xt, const f16* thw, const f16* phw,
                                              const f16* gwh, const float* thb, const float* phb,
                                              const float* gb, f16* th, f16* ph, f16* gt2){
    int b = blockIdx.y; int xx = blockIdx.x;
    int wv = threadIdx.x>>6, lane = threadIdx.x&63, q=lane>>4, cc=lane&15;
    if (xx < 64){
        // theta (xx<32) or phi (xx>=32), 128 rows per block
        int mat = xx>>5; int ntile = xx&31;
        int n0 = ntile*128 + wv*32;
        f16x8 aq[2][8];
        #pragma unroll
        for (int ns=0;ns<2;ns++){
            const f16* ap = xt + ((size_t)(b*NN + n0 + ns*16 + cc))*CC + q*8;
            #pragma unroll
            for (int kk=0;kk<8;kk++) aq[ns][kk] = *(const f16x8*)(ap + kk*32);
        }
        const f16* w   = mat? phw : thw;
        const float* bias = mat? phb : thb;
        f16* o = mat? ph : th;
        #pragma unroll 2
        for (int os=0;os<8;os++){
            f32x4 acc0={0,0,0,0}, acc1={0,0,0,0};
            const f16* wp = w + ((size_t)(os*16 + cc))*CC + q*8;
            #pragma unroll
            for (int kk=0;kk<8;kk++){
                f16x8 bf = *(const f16x8*)(wp + kk*32);
                acc0 = MFMA(aq[0][kk], bf, acc0);
                acc1 = MFMA(aq[1][kk], bf, acc1);
            }
            float bv = bias[os*16+cc];
            #pragma unroll
            for (int r=0;r<4;r++){
                o[((size_t)(b*NN + n0      + 4*q + r))*CI + os*16 + cc] = (f16)(acc0[r] + bv);
                o[((size_t)(b*NN + n0 + 16 + 4*q + r))*CI + os*16 + cc] = (f16)(acc1[r] + bv);
            }
        }
    } else {
        // g projection, TILED + key-permuted output
        int mt = xx - 64;
        f16x8 ag[2][8];
        #pragma unroll
        for (int os=0;os<2;os++){
            const f16* ap = gwh + ((size_t)(wv*32 + os*16 + cc))*CC + q*8;
            #pragma unroll
            for (int kk=0;kk<8;kk++) ag[os][kk] = *(const f16x8*)(ap + kk*32);
        }
        f32x4 acc[2][4];
        #pragma unroll
        for (int os=0;os<2;os++){
            #pragma unroll
            for (int ms=0;ms<4;ms++) acc[os][ms]=(f32x4){0,0,0,0};
        }
        #pragma unroll 2
        for (int kk=0;kk<8;kk++){
            #pragma unroll
            for (int ms=0;ms<4;ms++){
                f16x8 bf = *(const f16x8*)(xt + ((size_t)(b*NN + mt*64 + ms*16 + cc))*CC + kk*32 + q*8);
                acc[0][ms]=MFMA(ag[0][kk],bf,acc[0][ms]);
                acc[1][ms]=MFMA(ag[1][kk],bf,acc[1][ms]);
            }
        }
        // key within tile = ms*16+cc -> half h=ms>>1, permuted pos = 8*(cc>>2)+4*(ms&1)+(cc&3)
        #pragma unroll
        for (int os=0;os<2;os++){
            #pragma unroll
            for (int r=0;r<4;r++){
                int orow = wv*32 + os*16 + 4*q + r;
                float bv = gb[orow];
                #pragma unroll
                for (int ms=0;ms<4;ms++){
                    int pos = (ms>>1)*32 + 8*(cc>>2) + 4*(ms&1) + (cc&3);
                    gt2[((size_t)(b*64 + mt))*8192 + orow*64 + pos] = (f16)(acc[os][ms][r] + bv);
                }
            }
        }
    }
}

// ---------------- K3: flash attention, 32 q-rows/wave, KVBLK=64, swapped-P, 64KB LDS ----------------
__global__ __launch_bounds__(256, 2) void k3_attn(const f16* th, const f16* ph, const f16* gt2,
                                                  f16* ypart, float* ml){
    int qt = blockIdx.x;           // 32 q-tiles of 128 rows (4 waves x 32)
    int sp = blockIdx.y;           // 4 key splits of 1024 keys
    int b  = blockIdx.z;           // 4 batches
    int wv=threadIdx.x>>6, lane=threadIdx.x&63, q=lane>>4, cc=lane&15;
    int qrow0 = qt*128 + wv*32;
    int kv0 = sp*1024;
    int sw  = cc<<4;                        // phi read swizzle
    int rsw = (cc&7)<<4;                    // gt read swizzle (3-bit, bijective per 8-lane group)

    __shared__ __align__(16) char ldsb[65536];
    char* phL = ldsb;                 // [2][16384] phi [64 keys][256B], XOR-swizzled
    char* gtL = ldsb + 32768;         // [2][16384] gt [128 o][128B], XOR-swizzled (bits 4-6 by row&7)

    // theta B-fragments: lane holds theta[qrow0 + rb*16 + cc][d=q*8..]
    f16x8 aq[2][4];
    #pragma unroll
    for (int rb=0;rb<2;rb++){
        const f16* thp = th + ((size_t)(b*NN + qrow0 + rb*16 + cc))*CI + q*8;
        #pragma unroll
        for (int kk=0;kk<4;kk++) aq[rb][kk] = *(const f16x8*)(thp + kk*32);
    }

    const char* phg = (const char*)(ph + (size_t)b*NN*CI);
    const char* gtg = (const char*)gt2 + (size_t)b*64*16384;

    f32x4 yacc[2][8];
    #pragma unroll
    for (int rb=0;rb<2;rb++)
        #pragma unroll
        for (int os=0;os<8;os++) yacc[rb][os]=(f32x4){0,0,0,0};
    float m_run0=-1e30f, m_run1=-1e30f, l_run0=0.f, l_run1=0.f;

    // staging: 64-key tile tt -> buffer bb. LDS dest linear; global source pre-swizzled.
    auto STAGE = [&](int tt, int bb){
        int key0 = kv0 + tt*64;
        int mt  = key0 >> 6;
        char* pbase = phL + bb*16384 + wv*4096;
        char* gbase = gtL + bb*16384 + wv*4096;
        #pragma unroll
        for (int ch=0; ch<4; ch++){
            int prow = wv*16 + ch*4 + (lane>>4);
            const char* ps = phg + (size_t)(key0 + prow)*256 + (((lane&15)*16) ^ ((prow&15)<<4));
            __builtin_amdgcn_global_load_lds(GL1(ps), LDS3(pbase + ch*1024), 16, 0, 0);
            int gf = wv*4096 + ch*1024 + lane*16;
            int grow = gf>>7, gcol = gf&127;
            int scol = gcol ^ ((grow&7)<<4);
            const char* gs = gtg + (size_t)mt*16384 + grow*128 + scol;
            __builtin_amdgcn_global_load_lds(GL1(gs), LDS3(gbase + ch*1024), 16, 0, 0);
        }
    };

    STAGE(0, 0);
    __syncthreads();

    int cur = 0;
    #pragma unroll 1
    for (int it=0; it<16; ++it){
        if (it < 15) STAGE(it+1, cur^1);
        const char* pt  = phL + cur*16384;
        const char* gtt = gtL + cur*16384;
        // swapped QK^T: fa[rb][j][r] = score[key = 16j+4q+r][qrow = rb*16+cc]
        f32x4 fa[2][4];
        #pragma unroll
        for (int j=0;j<4;j++){
            f16x8 pf[4];
            #pragma unroll
            for (int kk=0;kk<4;kk++)
                pf[kk] = *(const f16x8*)(pt + (j*16+cc)*256 + ((kk*64 + q*16) ^ sw));
            fa[0][j]=(f32x4){0,0,0,0}; fa[1][j]=(f32x4){0,0,0,0};
            #pragma unroll
            for (int kk=0;kk<4;kk++){
                fa[0][j]=MFMA(pf[kk], aq[0][kk], fa[0][j]);
                fa[1][j]=MFMA(pf[kk], aq[1][kk], fa[1][j]);
            }
        }
        // per-row tile max: 15 in-lane fmax + 2 cross-q-group shuffles, per rb
        float mA0 = fmaxf(fmaxf(fa[0][0][0],fa[0][0][1]),fmaxf(fa[0][0][2],fa[0][0][3]));
        float mA1 = fmaxf(fmaxf(fa[0][1][0],fa[0][1][1]),fmaxf(fa[0][1][2],fa[0][1][3]));
        float mA2 = fmaxf(fmaxf(fa[0][2][0],fa[0][2][1]),fmaxf(fa[0][2][2],fa[0][2][3]));
        float mA3 = fmaxf(fmaxf(fa[0][3][0],fa[0][3][1]),fmaxf(fa[0][3][2],fa[0][3][3]));
        float mx0 = fmaxf(fmaxf(mA0,mA1),fmaxf(mA2,mA3));
        mx0 = fmaxf(mx0, __shfl_xor(mx0,16));
        mx0 = fmaxf(mx0, __shfl_xor(mx0,32));
        float mB0 = fmaxf(fmaxf(fa[1][0][0],fa[1][0][1]),fmaxf(fa[1][0][2],fa[1][0][3]));
        float mB1 = fmaxf(fmaxf(fa[1][1][0],fa[1][1][1]),fmaxf(fa[1][1][2],fa[1][1][3]));
        float mB2 = fmaxf(fmaxf(fa[1][2][0],fa[1][2][1]),fmaxf(fa[1][2][2],fa[1][2][3]));
        float mB3 = fmaxf(fmaxf(fa[1][3][0],fa[1][3][1]),fmaxf(fa[1][3][2],fa[1][3][3]));
        float mx1 = fmaxf(fmaxf(mB0,mB1),fmaxf(mB2,mB3));
        mx1 = fmaxf(mx1, __shfl_xor(mx1,16));
        mx1 = fmaxf(mx1, __shfl_xor(mx1,32));
        // defer-max skip (THR=3)
        float need = fmaxf(mx0 - m_run0, mx1 - m_run1);
        if (__any(need > 3.f)){
            float nm0 = fmaxf(m_run0, mx0), nm1 = fmaxf(m_run1, mx1);
            float co0 = __expf(m_run0 - nm0), co1 = __expf(m_run1 - nm1);
            m_run0 = nm0; m_run1 = nm1;
            l_run0 *= co0; l_run1 *= co1;
            #pragma unroll
            for (int os=0;os<8;os++){ yacc[0][os] *= co0; yacc[1][os] *= co1; }
        }
        #pragma unroll
        for (int j=0;j<4;j++){
            #pragma unroll
            for (int r=0;r<4;r++){
                fa[0][j][r] = __expf(fa[0][j][r]-m_run0);
                fa[1][j][r] = __expf(fa[1][j][r]-m_run1);
            }
        }
        l_run0 += ((fa[0][0][0]+fa[0][0][1]+fa[0][0][2]+fa[0][0][3])
                 + (fa[0][1][0]+fa[0][1][1]+fa[0][1][2]+fa[0][1][3]))
                + ((fa[0][2][0]+fa[0][2][1]+fa[0][2][2]+fa[0][2][3])
                 + (fa[0][3][0]+fa[0][3][1]+fa[0][3][2]+fa[0][3][3]));
        l_run1 += ((fa[1][0][0]+fa[1][0][1]+fa[1][0][2]+fa[1][0][3])
                 + (fa[1][1][0]+fa[1][1][1]+fa[1][1][2]+fa[1][1][3]))
                + ((fa[1][2][0]+fa[1][2][1]+fa[1][2][2]+fa[1][2][3])
                 + (fa[1][3][0]+fa[1][3][1]+fa[1][3][2]+fa[1][3][3]));
        // P in registers: half h frag element i=4j'+r -> fa[rb][2h+j'][r]
        f16x8 pb0h0, pb0h1, pb1h0, pb1h1;
        #pragma unroll
        for (int r=0;r<4;r++){
            pb0h0[r]=(f16)fa[0][0][r]; pb0h0[4+r]=(f16)fa[0][1][r];
            pb0h1[r]=(f16)fa[0][2][r]; pb0h1[4+r]=(f16)fa[0][3][r];
            pb1h0[r]=(f16)fa[1][0][r]; pb1h0[4+r]=(f16)fa[1][1][r];
            pb1h1[r]=(f16)fa[1][2][r]; pb1h1[4+r]=(f16)fa[1][3][r];
        }
        // PV: ga[h] read once per os, reused for both row-blocks (logical col XOR'd by row&7)
        #pragma unroll
        for (int os=0;os<8;os++){
            int row = os*16 + cc;
            f16x8 ga0 = *(const f16x8*)(gtt + row*128 + (((0<<6)|(q<<4)) ^ rsw));
            f16x8 ga1 = *(const f16x8*)(gtt + row*128 + (((1<<6)|(q<<4)) ^ rsw));
            yacc[0][os] = MFMA(ga0, pb0h0, yacc[0][os]);
            yacc[1][os] = MFMA(ga0, pb1h0, yacc[1][os]);
            yacc[0][os] = MFMA(ga1, pb0h1, yacc[0][os]);
            yacc[1][os] = MFMA(ga1, pb1h1, yacc[1][os]);
        }
        __syncthreads();
        cur ^= 1;
    }
    // final l reduce across q-groups
    float l0 = l_run0; l0 += __shfl_xor(l0,16); l0 += __shfl_xor(l0,32);
    float l1 = l_run1; l1 += __shfl_xor(l1,16); l1 += __shfl_xor(l1,32);
    float linv0 = 1.f/l0, linv1 = 1.f/l1;
    // transpose y^T frags through (now-free) staging LDS, then coalesced global write
    f16* yl = (f16*)(ldsb + wv*8192);   // per-wave 32 rows x 128 o x 2B
    #pragma unroll
    for (int os=0;os<8;os++){
        #pragma unroll
        for (int r=0;r<4;r++){
            int o = os*16 + 4*q + r;
            *(f16*)((char*)yl + cc*256      + ((o*2) ^ ((cc&7)<<4))) = (f16)(yacc[0][os][r]*linv0);
            *(f16*)((char*)yl + (16+cc)*256 + ((o*2) ^ ((cc&7)<<4))) = (f16)(yacc[1][os][r]*linv1);
        }
    }
    #pragma unroll
    for (int p=0;p<8;p++){
        int idx = p*512 + lane*8;
        int row = idx>>7, o0 = idx&127;
        f16x8 v = *(const f16x8*)((char*)yl + row*256 + ((o0*2) ^ ((row&7)<<4)));
        *(f16x8*)(ypart + ((size_t)((sp*4+b)*NN + qrow0 + row))*CI + o0) = v;
    }
    if (lane < 16){
        size_t row0 = (size_t)(sp*4+b)*NN + qrow0 + lane;
        ml[row0*2]        = m_run0;
        ml[row0*2+1]      = l0;
        ml[(row0+16)*2]   = m_run1;
        ml[(row0+16)*2+1] = l1;
    }
}

// ---------------- K3c: fused combine + Gram/mean stats (MFMA), 64 rows/block, 256 blocks ----------------
__global__ __launch_bounds__(256) void k3c(const f16* ypart, const float* ml,
                                           f16* y, float* part, float* mupart){
    int blk = blockIdx.x; int t = threadIdx.x;     // 256 blocks
    int rloc = t>>2;                   // 0..63
    int row  = blk*64 + rloc;
    int b = row>>12, n = row & 4095;
    int o0 = (t&3)*32;
    __shared__ __align__(16) f16 ldsT[128*64];     // [o][n'] n-swizzled
    float m_s[4], l_s[4];
    #pragma unroll
    for (int s=0;s<4;s++){ size_t r2 = ((size_t)(s*4+b)*NN + n)*2; m_s[s]=ml[r2]; l_s[s]=ml[r2+1]; }
    float M = fmaxf(fmaxf(m_s[0],m_s[1]),fmaxf(m_s[2],m_s[3]));
    float w[4]; float L=0.f;
    #pragma unroll
    for (int s=0;s<4;s++){ w[s]=l_s[s]*__expf(m_s[s]-M); L+=w[s]; }
    float inv = 1.f/L;
    #pragma unroll
    for (int s=0;s<4;s++) w[s]*=inv;
    float acc[32];
    #pragma unroll
    for (int j=0;j<32;j++) acc[j]=0.f;
    #pragma unroll
    for (int s=0;s<4;s++){
        const f16* src = ypart + ((size_t)(s*4+b)*NN + n)*CI + o0;
        #pragma unroll
        for (int v=0;v<4;v++){
            f16x8 vv = *(const f16x8*)(src + v*8);
            #pragma unroll
            for (int e=0;e<8;e++) acc[v*8+e] += w[s]*(float)vv[e];
        }
    }
    f16* yo = y + (size_t)row*CI + o0;
    #pragma unroll
    for (int v=0;v<4;v++){
        f16x8 ov;
        #pragma unroll
        for (int e=0;e<8;e++) ov[e] = (f16)acc[v*8+e];
        *(f16x8*)(yo + v*8) = ov;
        #pragma unroll
        for (int e=0;e<8;e++){
            int o = o0 + v*8 + e;
            ldsT[o*64 + (rloc ^ ((o&7)<<3))] = ov[e];
        }
    }
    __syncthreads();
    // Gram partial via MFMA over 64 rows
    int wv=t>>6, lane=t&63, q=lane>>4, cc=lane&15;
    f32x4 gacc[2][8];
    #pragma unroll
    for (int a=0;a<2;a++)
        #pragma unroll
        for (int c2=0;c2<8;c2++) gacc[a][c2]=(f32x4){0,0,0,0};
    f16x8 af[2][2];
    #pragma unroll
    for (int o1t=0;o1t<2;o1t++){
        int o1 = (wv*2+o1t)*16+cc;
        #pragma unroll
        for (int kk=0;kk<2;kk++)
            af[o1t][kk] = *(const f16x8*)(ldsT + o1*64 + ((kk*32+q*8) ^ ((o1&7)<<3)));
    }
    #pragma unroll 1
    for (int o2t=0;o2t<8;o2t++){
        int o2 = o2t*16+cc;
        #pragma unroll
        for (int kk=0;kk<2;kk++){
            f16x8 bf = *(const f16x8*)(ldsT + o2*64 + ((kk*32+q*8) ^ ((o2&7)<<3)));
            gacc[0][o2t] = MFMA(af[0][kk], bf, gacc[0][o2t]);
            gacc[1][o2t] = MFMA(af[1][kk], bf, gacc[1][o2t]);
        }
    }
    float* pb = part + (size_t)blk*16384;
    #pragma unroll
    for (int o1t=0;o1t<2;o1t++){
        #pragma unroll
        for (int o2t=0;o2t<8;o2t++){
            #pragma unroll
            for (int r=0;r<4;r++)
                pb[((wv*2+o1t)*16+4*q+r)*128 + o2t*16+cc] = gacc[o1t][o2t][r];
        }
    }
    // mean partial
    if (t<128){
        float sm=0.f;
        #pragma unroll
        for (int v=0;v<8;v++){
            f16x8 vv = *(const f16x8*)(ldsT + t*64 + ((v*8) ^ ((t&7)<<3)));
            #pragma unroll
            for (int e=0;e<8;e++) sm += (float)vv[e];
        }
        mupart[blk*128 + t] = sm;
    }
}

// ---------------- K4b: chunked reduce of partials -> atomicAdd into S (pre-zeroed) ----------------
__global__ __launch_bounds__(256) void k4b_red(const float* part, const float* mupart, float* S){
    int pc = blockIdx.y;               // 8 chunks of 32 partials
    int t = threadIdx.x;
    if (blockIdx.x < 64){
        int i = blockIdx.x*256 + t;
        float s=0.f;
        #pragma unroll 1
        for (int p=pc*32; p<pc*32+32; p++) s += part[(size_t)p*16384 + i];
        atomicAdd(&S[i], s);
    } else if (t < 128){
        float s=0.f;
        #pragma unroll 1
        for (int p=pc*32; p<pc*32+32; p++) s += mupart[p*128 + t];
        atomicAdd(&S[16384+t], s);
    }
}

// ---------------- K4c: BN coefficients A[ch], B4[ch] ----------------
__global__ __launch_bounds__(128) void k4c_coef(const float* S, const float* Ww, const float* Wb,
                                                const float* gamma, const float* beta,
                                                const float* scale, float* AB){
    int ch = blockIdx.x; int t = threadIdx.x;
    const float* w = Ww + ch*CI;
    float tmp=0.f;
    const float* Srow = S + t*CI;
    #pragma unroll 1
    for (int o2=0;o2<CI;o2++) tmp += Srow[o2]*w[o2];
    float v  = w[t]*tmp;
    float mc = w[t]*S[16384 + t];
    #pragma unroll
    for (int s=1;s<64;s<<=1){ v += __shfl_xor(v,s); mc += __shfl_xor(mc,s); }
    __shared__ float red[4];
    if ((t&63)==0){ red[(t>>6)*2]=v; red[(t>>6)*2+1]=mc; }
    __syncthreads();
    if (t==0){
        float wSw = red[0]+red[2];
        float wmu = red[1]+red[3];
        const float M = 16384.f;
        float meanwy = wmu/M + Wb[ch];
        float var = wSw/M - (wmu/M)*(wmu/M);
        float inv = rsqrtf(var + 1e-5f);
        float sc = scale[0];
        float A  = sc*gamma[ch]*inv;
        float B3 = sc*(beta[ch] - meanwy*inv*gamma[ch]);
        AB[ch]     = A;
        AB[256+ch] = B3 + A*Wb[ch];
    }
}

// ---------------- K5: fused W-conv + BN + scale + residual, 1024 blocks ----------------
__global__ __launch_bounds__(256) void k5_out(const f16* Wwh, const f16* y, const float* x,
                                              const float* AB, float* out){
    int ntile = blockIdx.x;      // 64
    int cht   = blockIdx.y;      // 4
    int b     = blockIdx.z;
    int wv=threadIdx.x>>6, lane=threadIdx.x&63, q=lane>>4, cc=lane&15;
    int ch0 = cht*64 + wv*16;
    f16x8 aw[4];
    const f16* wp = Wwh + ((size_t)(ch0+cc))*CI + q*8;
    #pragma unroll
    for (int kk=0;kk<4;kk++) aw[kk]=*(const f16x8*)(wp+kk*32);
    float Ar[4], Br[4];
    #pragma unroll
    for (int r=0;r<4;r++){ Ar[r]=AB[ch0+4*q+r]; Br[r]=AB[256+ch0+4*q+r]; }
    #pragma unroll 1
    for (int ns=0;ns<4;ns++){
        int n0 = ntile*64 + ns*16;
        f32x4 acc={0,0,0,0};
        const f16* yp = y + ((size_t)(b*NN + n0 + cc))*CI + q*8;
        #pragma unroll
        for (int kk=0;kk<4;kk++) acc = MFMA(aw[kk], *(const f16x8*)(yp+kk*32), acc);
        #pragma unroll
        for (int r=0;r<4;r++){
            size_t addr = ((size_t)(b*CC + ch0 + 4*q + r))*NN + n0 + cc;
            out[addr] = x[addr] + Ar[r]*acc[r] + Br[r];
        }
    }
}

extern "C" void kernel_launch(void* const* d_in, const int* in_sizes, int n_in,
                              void* d_out, int out_size, void* d_ws, size_t ws_size,
                              hipStream_t stream){
    const float* x    = (const float*)d_in[0];
    const float* g_w  = (const float*)d_in[1];
    const float* g_b  = (const float*)d_in[2];
    const float* th_w = (const float*)d_in[3];
    const float* th_b = (const float*)d_in[4];
    const float* ph_w = (const float*)d_in[5];
    const float* ph_b = (const float*)d_in[6];
    const float* W_w  = (const float*)d_in[7];
    const float* W_b  = (const float*)d_in[8];
    const float* bg   = (const float*)d_in[9];
    const float* bb   = (const float*)d_in[10];
    const float* sc   = (const float*)d_in[11];

    char* ws = (char*)d_ws;
    f16* xt  = (f16*)(ws);                                  // 8.4 MB
    f16* th  = (f16*)(ws + 8388608);                        // 4.2 MB
    f16* ph  = (f16*)(ws + 8388608 + 1*4194304);            // 4.2 MB
    f16* gt2 = (f16*)(ws + 8388608 + 2*4194304);            // 4.2 MB (tiled [b][mt][128][64], key-permuted)
    f16* y   = (f16*)(ws + 8388608 + 3*4194304);            // 4.2 MB
    f16* wh  = (f16*)(ws + 8388608 + 4*4194304);            // 256 KB
    float* ml    = (float*)(ws + 25427968);                 // 512 KB
    f16*   ypart = (f16*)(ws + 25952256);                   // 16.8 MB
    float* mupart= (float*)(ws + 42729472);                 // 128 KB
    float* part  = (float*)ws;                              // 16.8 MB overlay on xt+th+ph (dead after k3)
    float* S    = (float*)(ws + 42860544);                  // 66 KB
    float* AB   = (float*)(ws + 42926592);                  // 2 KB
    f16* th_wh = wh;
    f16* ph_wh = wh + 32768;
    f16* g_wh  = wh + 65536;
    f16* Ww_h  = wh + 98304;

    hipMemsetAsync(S, 0, 16512*sizeof(float), stream);
    hipLaunchKernelGGL(k01_xpose, dim3(64,4,4), dim3(256), 0, stream, x, xt, th_w, ph_w, g_w, W_w, wh);
    hipLaunchKernelGGL(k2_all,   dim3(128,4),   dim3(256), 0, stream, xt, th_wh, ph_wh, g_wh,
                       th_b, ph_b, g_b, th, ph, gt2);
    hipLaunchKernelGGL(k3_attn,  dim3(32,4,4),  dim3(256), 0, stream, th, ph, gt2, ypart, ml);
    hipLaunchKernelGGL(k3c,      dim3(256),     dim3(256), 0, stream, ypart, ml, y, part, mupart);
    hipLaunchKernelGGL(k4b_red,  dim3(65,8),    dim3(256), 0, stream, part, mupart, S);
    hipLaunchKernelGGL(k4c_coef, dim3(256),     dim3(128), 0, stream, S, W_w, W_b, bg, bb, sc, AB);
    hipLaunchKernelGGL(k5_out,   dim3(64,4,4),  dim3(256), 0, stream, Ww_h, y, x, AB, (float*)d_out);
}

// Round 19
// 135.476 us; speedup vs baseline: 1.1001x; 1.0024x over previous
//
#include <hip/hip_runtime.h>
#include <hip/hip_bf16.h>

#define BB 4
#define CC 256
#define CI 128
#define NN 4096

typedef _Float16 f16;
typedef __attribute__((ext_vector_type(8))) _Float16 f16x8;
typedef __attribute__((ext_vector_type(4))) _Float16 f16x4;
typedef __attribute__((ext_vector_type(4))) float f32x4;

#define MFMA(a,b,c) __builtin_amdgcn_mfma_f32_16x16x32_f16(a,b,c,0,0,0)
#define LDS3(p) ((__attribute__((address_space(3))) void*)(p))
#define GL1(p)  ((const __attribute__((address_space(1))) void*)(p))

// ---------------- K01: transpose+cast x -> xt, plus weight cast (fused k0) ----------------
__global__ __launch_bounds__(256) void k01_xpose(const float* x, f16* xt,
                                                 const float* tw, const float* pw,
                                                 const float* gw, const float* Ww, f16* wdst){
    int nt = blockIdx.x, ct = blockIdx.y, b = blockIdx.z;
    __shared__ float tile[64][65];
    int t = threadIdx.x;
    const float* src = x + ((size_t)(b*CC + ct*64))*NN + nt*64;
    #pragma unroll
    for (int k=0;k<16;k++){ int idx=t+k*256; int cl=idx>>6, nl=idx&63;
        tile[cl][nl]=src[(size_t)cl*NN + nl]; }
    __syncthreads();
    f16* dst = xt + ((size_t)(b*NN + nt*64))*CC + ct*64;
    #pragma unroll
    for (int k=0;k<16;k++){ int idx=t+k*256; int nl=idx>>6, cl=idx&63;
        dst[(size_t)nl*CC + cl] = (f16)tile[cl][nl]; }
    // fused weight cast: 1024 blocks x 128 elements = 131072
    if (t < 128){
        int blkId = blockIdx.x + 64*(blockIdx.y + 4*blockIdx.z);
        int i = blkId*128 + t;
        int j = i & 32767; int sel = i >> 15;
        const float* s = (sel==0)? tw : (sel==1)? pw : (sel==2)? gw : Ww;
        wdst[i] = (f16)s[j];
    }
}

// ---------------- K2: merged theta/phi/g projections, 512 blocks ----------------
// g output gt2[b][mt][o][64] with keys PERMUTED within each 32-half:
// key K=16j+4a+r stored at p = 8a+4j+r  (so k3's PV A-frag is one b128).
__global__ __launch_bounds__(256) void k2_all(const f16* xt, const f16* thw, const f16* phw,
                                              const f16* gwh, const float* thb, const float* phb,
                                              const float* gb, f16* th, f16* ph, f16* gt2){
    int b = blockIdx.y; int xx = blockIdx.x;
    int wv = threadIdx.x>>6, lane = threadIdx.x&63, q=lane>>4, cc=lane&15;
    if (xx < 64){
        // theta (xx<32) or phi (xx>=32), 128 rows per block
        int mat = xx>>5; int ntile = xx&31;
        int n0 = ntile*128 + wv*32;
        f16x8 aq[2][8];
        #pragma unroll
        for (int ns=0;ns<2;ns++){
            const f16* ap = xt + ((size_t)(b*NN + n0 + ns*16 + cc))*CC + q*8;
            #pragma unroll
            for (int kk=0;kk<8;kk++) aq[ns][kk] = *(const f16x8*)(ap + kk*32);
        }
        const f16* w   = mat? phw : thw;
        const float* bias = mat? phb : thb;
        f16* o = mat? ph : th;
        #pragma unroll 2
        for (int os=0;os<8;os++){
            f32x4 acc0={0,0,0,0}, acc1={0,0,0,0};
            const f16* wp = w + ((size_t)(os*16 + cc))*CC + q*8;
            #pragma unroll
            for (int kk=0;kk<8;kk++){
                f16x8 bf = *(const f16x8*)(wp + kk*32);
                acc0 = MFMA(aq[0][kk], bf, acc0);
                acc1 = MFMA(aq[1][kk], bf, acc1);
            }
            float bv = bias[os*16+cc];
            #pragma unroll
            for (int r=0;r<4;r++){
                o[((size_t)(b*NN + n0      + 4*q + r))*CI + os*16 + cc] = (f16)(acc0[r] + bv);
                o[((size_t)(b*NN + n0 + 16 + 4*q + r))*CI + os*16 + cc] = (f16)(acc1[r] + bv);
            }
        }
    } else {
        // g projection, TILED + key-permuted output
        int mt = xx - 64;
        f16x8 ag[2][8];
        #pragma unroll
        for (int os=0;os<2;os++){
            const f16* ap = gwh + ((size_t)(wv*32 + os*16 + cc))*CC + q*8;
            #pragma unroll
            for (int kk=0;kk<8;kk++) ag[os][kk] = *(const f16x8*)(ap + kk*32);
        }
        f32x4 acc[2][4];
        #pragma unroll
        for (int os=0;os<2;os++){
            #pragma unroll
            for (int ms=0;ms<4;ms++) acc[os][ms]=(f32x4){0,0,0,0};
        }
        #pragma unroll 2
        for (int kk=0;kk<8;kk++){
            #pragma unroll
            for (int ms=0;ms<4;ms++){
                f16x8 bf = *(const f16x8*)(xt + ((size_t)(b*NN + mt*64 + ms*16 + cc))*CC + kk*32 + q*8);
                acc[0][ms]=MFMA(ag[0][kk],bf,acc[0][ms]);
                acc[1][ms]=MFMA(ag[1][kk],bf,acc[1][ms]);
            }
        }
        // key within tile = ms*16+cc -> half h=ms>>1, permuted pos = 8*(cc>>2)+4*(ms&1)+(cc&3)
        #pragma unroll
        for (int os=0;os<2;os++){
            #pragma unroll
            for (int r=0;r<4;r++){
                int orow = wv*32 + os*16 + 4*q + r;
                float bv = gb[orow];
                #pragma unroll
                for (int ms=0;ms<4;ms++){
                    int pos = (ms>>1)*32 + 8*(cc>>2) + 4*(ms&1) + (cc&3);
                    gt2[((size_t)(b*64 + mt))*8192 + orow*64 + pos] = (f16)(acc[os][ms][r] + bv);
                }
            }
        }
    }
}

// ---------------- K3: flash attention, 32 q-rows/wave, KVBLK=64, swapped-P, 64KB LDS ----------------
__global__ __launch_bounds__(256, 2) void k3_attn(const f16* th, const f16* ph, const f16* gt2,
                                                  f16* ypart, float* ml){
    int qt = blockIdx.x;           // 32 q-tiles of 128 rows (4 waves x 32)
    int sp = blockIdx.y;           // 4 key splits of 1024 keys
    int b  = blockIdx.z;           // 4 batches
    int wv=threadIdx.x>>6, lane=threadIdx.x&63, q=lane>>4, cc=lane&15;
    int qrow0 = qt*128 + wv*32;
    int kv0 = sp*1024;
    int sw  = cc<<4;                        // phi read swizzle
    int rsw = (cc&7)<<4;                    // gt read swizzle (3-bit, bijective per 8-lane group)

    __shared__ __align__(16) char ldsb[65536];
    char* phL = ldsb;                 // [2][16384] phi [64 keys][256B], XOR-swizzled
    char* gtL = ldsb + 32768;         // [2][16384] gt [128 o][128B], XOR-swizzled (bits 4-6 by row&7)

    // theta B-fragments: lane holds theta[qrow0 + rb*16 + cc][d=q*8..]
    f16x8 aq[2][4];
    #pragma unroll
    for (int rb=0;rb<2;rb++){
        const f16* thp = th + ((size_t)(b*NN + qrow0 + rb*16 + cc))*CI + q*8;
        #pragma unroll
        for (int kk=0;kk<4;kk++) aq[rb][kk] = *(const f16x8*)(thp + kk*32);
    }

    const char* phg = (const char*)(ph + (size_t)b*NN*CI);
    const char* gtg = (const char*)gt2 + (size_t)b*64*16384;

    f32x4 yacc[2][8];
    #pragma unroll
    for (int rb=0;rb<2;rb++)
        #pragma unroll
        for (int os=0;os<8;os++) yacc[rb][os]=(f32x4){0,0,0,0};
    float m_run0=-1e30f, m_run1=-1e30f, l_run0=0.f, l_run1=0.f;

    // staging: 64-key tile tt -> buffer bb. LDS dest linear; global source pre-swizzled.
    auto STAGE = [&](int tt, int bb){
        int key0 = kv0 + tt*64;
        int mt  = key0 >> 6;
        char* pbase = phL + bb*16384 + wv*4096;
        char* gbase = gtL + bb*16384 + wv*4096;
        #pragma unroll
        for (int ch=0; ch<4; ch++){
            int prow = wv*16 + ch*4 + (lane>>4);
            const char* ps = phg + (size_t)(key0 + prow)*256 + (((lane&15)*16) ^ ((prow&15)<<4));
            __builtin_amdgcn_global_load_lds(GL1(ps), LDS3(pbase + ch*1024), 16, 0, 0);
            int gf = wv*4096 + ch*1024 + lane*16;
            int grow = gf>>7, gcol = gf&127;
            int scol = gcol ^ ((grow&7)<<4);
            const char* gs = gtg + (size_t)mt*16384 + grow*128 + scol;
            __builtin_amdgcn_global_load_lds(GL1(gs), LDS3(gbase + ch*1024), 16, 0, 0);
        }
    };

    STAGE(0, 0);
    __syncthreads();

    int cur = 0;
    #pragma unroll 1
    for (int it=0; it<16; ++it){
        if (it < 15) STAGE(it+1, cur^1);
        const char* pt  = phL + cur*16384;
        const char* gtt = gtL + cur*16384;
        // swapped QK^T: fa[rb][j][r] = score[key = 16j+4q+r][qrow = rb*16+cc]
        f32x4 fa[2][4];
        __builtin_amdgcn_s_setprio(1);
        #pragma unroll
        for (int j=0;j<4;j++){
            f16x8 pf[4];
            #pragma unroll
            for (int kk=0;kk<4;kk++)
                pf[kk] = *(const f16x8*)(pt + (j*16+cc)*256 + ((kk*64 + q*16) ^ sw));
            fa[0][j]=(f32x4){0,0,0,0}; fa[1][j]=(f32x4){0,0,0,0};
            #pragma unroll
            for (int kk=0;kk<4;kk++){
                fa[0][j]=MFMA(pf[kk], aq[0][kk], fa[0][j]);
                fa[1][j]=MFMA(pf[kk], aq[1][kk], fa[1][j]);
            }
        }
        __builtin_amdgcn_s_setprio(0);
        // per-row tile max: 15 in-lane fmax + 2 cross-q-group shuffles, per rb
        float mA0 = fmaxf(fmaxf(fa[0][0][0],fa[0][0][1]),fmaxf(fa[0][0][2],fa[0][0][3]));
        float mA1 = fmaxf(fmaxf(fa[0][1][0],fa[0][1][1]),fmaxf(fa[0][1][2],fa[0][1][3]));
        float mA2 = fmaxf(fmaxf(fa[0][2][0],fa[0][2][1]),fmaxf(fa[0][2][2],fa[0][2][3]));
        float mA3 = fmaxf(fmaxf(fa[0][3][0],fa[0][3][1]),fmaxf(fa[0][3][2],fa[0][3][3]));
        float mx0 = fmaxf(fmaxf(mA0,mA1),fmaxf(mA2,mA3));
        mx0 = fmaxf(mx0, __shfl_xor(mx0,16));
        mx0 = fmaxf(mx0, __shfl_xor(mx0,32));
        float mB0 = fmaxf(fmaxf(fa[1][0][0],fa[1][0][1]),fmaxf(fa[1][0][2],fa[1][0][3]));
        float mB1 = fmaxf(fmaxf(fa[1][1][0],fa[1][1][1]),fmaxf(fa[1][1][2],fa[1][1][3]));
        float mB2 = fmaxf(fmaxf(fa[1][2][0],fa[1][2][1]),fmaxf(fa[1][2][2],fa[1][2][3]));
        float mB3 = fmaxf(fmaxf(fa[1][3][0],fa[1][3][1]),fmaxf(fa[1][3][2],fa[1][3][3]));
        float mx1 = fmaxf(fmaxf(mB0,mB1),fmaxf(mB2,mB3));
        mx1 = fmaxf(mx1, __shfl_xor(mx1,16));
        mx1 = fmaxf(mx1, __shfl_xor(mx1,32));
        // defer-max skip (THR=3)
        float need = fmaxf(mx0 - m_run0, mx1 - m_run1);
        if (__any(need > 3.f)){
            float nm0 = fmaxf(m_run0, mx0), nm1 = fmaxf(m_run1, mx1);
            float co0 = __expf(m_run0 - nm0), co1 = __expf(m_run1 - nm1);
            m_run0 = nm0; m_run1 = nm1;
            l_run0 *= co0; l_run1 *= co1;
            #pragma unroll
            for (int os=0;os<8;os++){ yacc[0][os] *= co0; yacc[1][os] *= co1; }
        }
        #pragma unroll
        for (int j=0;j<4;j++){
            #pragma unroll
            for (int r=0;r<4;r++){
                fa[0][j][r] = __expf(fa[0][j][r]-m_run0);
                fa[1][j][r] = __expf(fa[1][j][r]-m_run1);
            }
        }
        l_run0 += ((fa[0][0][0]+fa[0][0][1]+fa[0][0][2]+fa[0][0][3])
                 + (fa[0][1][0]+fa[0][1][1]+fa[0][1][2]+fa[0][1][3]))
                + ((fa[0][2][0]+fa[0][2][1]+fa[0][2][2]+fa[0][2][3])
                 + (fa[0][3][0]+fa[0][3][1]+fa[0][3][2]+fa[0][3][3]));
        l_run1 += ((fa[1][0][0]+fa[1][0][1]+fa[1][0][2]+fa[1][0][3])
                 + (fa[1][1][0]+fa[1][1][1]+fa[1][1][2]+fa[1][1][3]))
                + ((fa[1][2][0]+fa[1][2][1]+fa[1][2][2]+fa[1][2][3])
                 + (fa[1][3][0]+fa[1][3][1]+fa[1][3][2]+fa[1][3][3]));
        // P in registers: half h frag element i=4j'+r -> fa[rb][2h+j'][r]
        f16x8 pb0h0, pb0h1, pb1h0, pb1h1;
        #pragma unroll
        for (int r=0;r<4;r++){
            pb0h0[r]=(f16)fa[0][0][r]; pb0h0[4+r]=(f16)fa[0][1][r];
            pb0h1[r]=(f16)fa[0][2][r]; pb0h1[4+r]=(f16)fa[0][3][r];
            pb1h0[r]=(f16)fa[1][0][r]; pb1h0[4+r]=(f16)fa[1][1][r];
            pb1h1[r]=(f16)fa[1][2][r]; pb1h1[4+r]=(f16)fa[1][3][r];
        }
        // PV: ga[h] read once per os, reused for both row-blocks (logical col XOR'd by row&7)
        __builtin_amdgcn_s_setprio(1);
        #pragma unroll
        for (int os=0;os<8;os++){
            int row = os*16 + cc;
            f16x8 ga0 = *(const f16x8*)(gtt + row*128 + (((0<<6)|(q<<4)) ^ rsw));
            f16x8 ga1 = *(const f16x8*)(gtt + row*128 + (((1<<6)|(q<<4)) ^ rsw));
            yacc[0][os] = MFMA(ga0, pb0h0, yacc[0][os]);
            yacc[1][os] = MFMA(ga0, pb1h0, yacc[1][os]);
            yacc[0][os] = MFMA(ga1, pb0h1, yacc[0][os]);
            yacc[1][os] = MFMA(ga1, pb1h1, yacc[1][os]);
        }
        __builtin_amdgcn_s_setprio(0);
        __syncthreads();
        cur ^= 1;
    }
    // final l reduce across q-groups
    float l0 = l_run0; l0 += __shfl_xor(l0,16); l0 += __shfl_xor(l0,32);
    float l1 = l_run1; l1 += __shfl_xor(l1,16); l1 += __shfl_xor(l1,32);
    float linv0 = 1.f/l0, linv1 = 1.f/l1;
    // transpose y^T frags through (now-free) staging LDS, then coalesced global write
    f16* yl = (f16*)(ldsb + wv*8192);   // per-wave 32 rows x 128 o x 2B
    #pragma unroll
    for (int os=0;os<8;os++){
        #pragma unroll
        for (int r=0;r<4;r++){
            int o = os*16 + 4*q + r;
            *(f16*)((char*)yl + cc*256      + ((o*2) ^ ((cc&7)<<4))) = (f16)(yacc[0][os][r]*linv0);
            *(f16*)((char*)yl + (16+cc)*256 + ((o*2) ^ ((cc&7)<<4))) = (f16)(yacc[1][os][r]*linv1);
        }
    }
    #pragma unroll
    for (int p=0;p<8;p++){
        int idx = p*512 + lane*8;
        int row = idx>>7, o0 = idx&127;
        f16x8 v = *(const f16x8*)((char*)yl + row*256 + ((o0*2) ^ ((row&7)<<4)));
        *(f16x8*)(ypart + ((size_t)((sp*4+b)*NN + qrow0 + row))*CI + o0) = v;
    }
    if (lane < 16){
        size_t row0 = (size_t)(sp*4+b)*NN + qrow0 + lane;
        ml[row0*2]        = m_run0;
        ml[row0*2+1]      = l0;
        ml[(row0+16)*2]   = m_run1;
        ml[(row0+16)*2+1] = l1;
    }
}

// ---------------- K3c: fused combine + Gram/mean stats (MFMA), 64 rows/block, 256 blocks ----------------
__global__ __launch_bounds__(256) void k3c(const f16* ypart, const float* ml,
                                           f16* y, float* part, float* mupart){
    int blk = blockIdx.x; int t = threadIdx.x;     // 256 blocks
    int rloc = t>>2;                   // 0..63
    int row  = blk*64 + rloc;
    int b = row>>12, n = row & 4095;
    int o0 = (t&3)*32;
    __shared__ __align__(16) f16 ldsT[128*64];     // [o][n'] n-swizzled
    float m_s[4], l_s[4];
    #pragma unroll
    for (int s=0;s<4;s++){ size_t r2 = ((size_t)(s*4+b)*NN + n)*2; m_s[s]=ml[r2]; l_s[s]=ml[r2+1]; }
    float M = fmaxf(fmaxf(m_s[0],m_s[1]),fmaxf(m_s[2],m_s[3]));
    float w[4]; float L=0.f;
    #pragma unroll
    for (int s=0;s<4;s++){ w[s]=l_s[s]*__expf(m_s[s]-M); L+=w[s]; }
    float inv = 1.f/L;
    #pragma unroll
    for (int s=0;s<4;s++) w[s]*=inv;
    float acc[32];
    #pragma unroll
    for (int j=0;j<32;j++) acc[j]=0.f;
    #pragma unroll
    for (int s=0;s<4;s++){
        const f16* src = ypart + ((size_t)(s*4+b)*NN + n)*CI + o0;
        #pragma unroll
        for (int v=0;v<4;v++){
            f16x8 vv = *(const f16x8*)(src + v*8);
            #pragma unroll
            for (int e=0;e<8;e++) acc[v*8+e] += w[s]*(float)vv[e];
        }
    }
    f16* yo = y + (size_t)row*CI + o0;
    #pragma unroll
    for (int v=0;v<4;v++){
        f16x8 ov;
        #pragma unroll
        for (int e=0;e<8;e++) ov[e] = (f16)acc[v*8+e];
        *(f16x8*)(yo + v*8) = ov;
        #pragma unroll
        for (int e=0;e<8;e++){
            int o = o0 + v*8 + e;
            ldsT[o*64 + (rloc ^ ((o&7)<<3))] = ov[e];
        }
    }
    __syncthreads();
    // Gram partial via MFMA over 64 rows
    int wv=t>>6, lane=t&63, q=lane>>4, cc=lane&15;
    f32x4 gacc[2][8];
    #pragma unroll
    for (int a=0;a<2;a++)
        #pragma unroll
        for (int c2=0;c2<8;c2++) gacc[a][c2]=(f32x4){0,0,0,0};
    f16x8 af[2][2];
    #pragma unroll
    for (int o1t=0;o1t<2;o1t++){
        int o1 = (wv*2+o1t)*16+cc;
        #pragma unroll
        for (int kk=0;kk<2;kk++)
            af[o1t][kk] = *(const f16x8*)(ldsT + o1*64 + ((kk*32+q*8) ^ ((o1&7)<<3)));
    }
    #pragma unroll 1
    for (int o2t=0;o2t<8;o2t++){
        int o2 = o2t*16+cc;
        #pragma unroll
        for (int kk=0;kk<2;kk++){
            f16x8 bf = *(const f16x8*)(ldsT + o2*64 + ((kk*32+q*8) ^ ((o2&7)<<3)));
            gacc[0][o2t] = MFMA(af[0][kk], bf, gacc[0][o2t]);
            gacc[1][o2t] = MFMA(af[1][kk], bf, gacc[1][o2t]);
        }
    }
    float* pb = part + (size_t)blk*16384;
    #pragma unroll
    for (int o1t=0;o1t<2;o1t++){
        #pragma unroll
        for (int o2t=0;o2t<8;o2t++){
            #pragma unroll
            for (int r=0;r<4;r++)
                pb[((wv*2+o1t)*16+4*q+r)*128 + o2t*16+cc] = gacc[o1t][o2t][r];
        }
    }
    // mean partial
    if (t<128){
        float sm=0.f;
        #pragma unroll
        for (int v=0;v<8;v++){
            f16x8 vv = *(const f16x8*)(ldsT + t*64 + ((v*8) ^ ((t&7)<<3)));
            #pragma unroll
            for (int e=0;e<8;e++) sm += (float)vv[e];
        }
        mupart[blk*128 + t] = sm;
    }
}

// ---------------- K4b: chunked reduce of partials -> atomicAdd into S (pre-zeroed) ----------------
__global__ __launch_bounds__(256) void k4b_red(const float* part, const float* mupart, float* S){
    int pc = blockIdx.y;               // 8 chunks of 32 partials
    int t = threadIdx.x;
    if (blockIdx.x < 64){
        int i = blockIdx.x*256 + t;
        float s=0.f;
        #pragma unroll 1
        for (int p=pc*32; p<pc*32+32; p++) s += part[(size_t)p*16384 + i];
        atomicAdd(&S[i], s);
    } else if (t < 128){
        float s=0.f;
        #pragma unroll 1
        for (int p=pc*32; p<pc*32+32; p++) s += mupart[p*128 + t];
        atomicAdd(&S[16384+t], s);
    }
}

// ---------------- K4c: BN coefficients A[ch], B4[ch] ----------------
__global__ __launch_bounds__(128) void k4c_coef(const float* S, const float* Ww, const float* Wb,
                                                const float* gamma, const float* beta,
                                                const float* scale, float* AB){
    int ch = blockIdx.x; int t = threadIdx.x;
    const float* w = Ww + ch*CI;
    float tmp=0.f;
    const float* Srow = S + t*CI;
    #pragma unroll 1
    for (int o2=0;o2<CI;o2++) tmp += Srow[o2]*w[o2];
    float v  = w[t]*tmp;
    float mc = w[t]*S[16384 + t];
    #pragma unroll
    for (int s=1;s<64;s<<=1){ v += __shfl_xor(v,s); mc += __shfl_xor(mc,s); }
    __shared__ float red[4];
    if ((t&63)==0){ red[(t>>6)*2]=v; red[(t>>6)*2+1]=mc; }
    __syncthreads();
    if (t==0){
        float wSw = red[0]+red[2];
        float wmu = red[1]+red[3];
        const float M = 16384.f;
        float meanwy = wmu/M + Wb[ch];
        float var = wSw/M - (wmu/M)*(wmu/M);
        float inv = rsqrtf(var + 1e-5f);
        float sc = scale[0];
        float A  = sc*gamma[ch]*inv;
        float B3 = sc*(beta[ch] - meanwy*inv*gamma[ch]);
        AB[ch]     = A;
        AB[256+ch] = B3 + A*Wb[ch];
    }
}

// ---------------- K5: fused W-conv + BN + scale + residual, 1024 blocks ----------------
__global__ __launch_bounds__(256) void k5_out(const f16* Wwh, const f16* y, const float* x,
                                              const float* AB, float* out){
    int ntile = blockIdx.x;      // 64
    int cht   = blockIdx.y;      // 4
    int b     = blockIdx.z;
    int wv=threadIdx.x>>6, lane=threadIdx.x&63, q=lane>>4, cc=lane&15;
    int ch0 = cht*64 + wv*16;
    f16x8 aw[4];
    const f16* wp = Wwh + ((size_t)(ch0+cc))*CI + q*8;
    #pragma unroll
    for (int kk=0;kk<4;kk++) aw[kk]=*(const f16x8*)(wp+kk*32);
    float Ar[4], Br[4];
    #pragma unroll
    for (int r=0;r<4;r++){ Ar[r]=AB[ch0+4*q+r]; Br[r]=AB[256+ch0+4*q+r]; }
    #pragma unroll 1
    for (int ns=0;ns<4;ns++){
        int n0 = ntile*64 + ns*16;
        f32x4 acc={0,0,0,0};
        const f16* yp = y + ((size_t)(b*NN + n0 + cc))*CI + q*8;
        #pragma unroll
        for (int kk=0;kk<4;kk++) acc = MFMA(aw[kk], *(const f16x8*)(yp+kk*32), acc);
        #pragma unroll
        for (int r=0;r<4;r++){
            size_t addr = ((size_t)(b*CC + ch0 + 4*q + r))*NN + n0 + cc;
            out[addr] = x[addr] + Ar[r]*acc[r] + Br[r];
        }
    }
}

extern "C" void kernel_launch(void* const* d_in, const int* in_sizes, int n_in,
                              void* d_out, int out_size, void* d_ws, size_t ws_size,
                              hipStream_t stream){
    const float* x    = (const float*)d_in[0];
    const float* g_w  = (const float*)d_in[1];
    const float* g_b  = (const float*)d_in[2];
    const float* th_w = (const float*)d_in[3];
    const float* th_b = (const float*)d_in[4];
    const float* ph_w = (const float*)d_in[5];
    const float* ph_b = (const float*)d_in[6];
    const float* W_w  = (const float*)d_in[7];
    const float* W_b  = (const float*)d_in[8];
    const float* bg   = (const float*)d_in[9];
    const float* bb   = (const float*)d_in[10];
    const float* sc   = (const float*)d_in[11];

    char* ws = (char*)d_ws;
    f16* xt  = (f16*)(ws);                                  // 8.4 MB
    f16* th  = (f16*)(ws + 8388608);                        // 4.2 MB
    f16* ph  = (f16*)(ws + 8388608 + 1*4194304);            // 4.2 MB
    f16* gt2 = (f16*)(ws + 8388608 + 2*4194304);            // 4.2 MB (tiled [b][mt][128][64], key-permuted)
    f16* y   = (f16*)(ws + 8388608 + 3*4194304);            // 4.2 MB
    f16* wh  = (f16*)(ws + 8388608 + 4*4194304);            // 256 KB
    float* ml    = (float*)(ws + 25427968);                 // 512 KB
    f16*   ypart = (f16*)(ws + 25952256);                   // 16.8 MB
    float* mupart= (float*)(ws + 42729472);                 // 128 KB
    float* part  = (float*)ws;                              // 16.8 MB overlay on xt+th+ph (dead after k3)
    float* S    = (float*)(ws + 42860544);                  // 66 KB
    float* AB   = (float*)(ws + 42926592);                  // 2 KB
    f16* th_wh = wh;
    f16* ph_wh = wh + 32768;
    f16* g_wh  = wh + 65536;
    f16* Ww_h  = wh + 98304;

    hipMemsetAsync(S, 0, 16512*sizeof(float), stream);
    hipLaunchKernelGGL(k01_xpose, dim3(64,4,4), dim3(256), 0, stream, x, xt, th_w, ph_w, g_w, W_w, wh);
    hipLaunchKernelGGL(k2_all,   dim3(128,4),   dim3(256), 0, stream, xt, th_wh, ph_wh, g_wh,
                       th_b, ph_b, g_b, th, ph, gt2);
    hipLaunchKernelGGL(k3_attn,  dim3(32,4,4),  dim3(256), 0, stream, th, ph, gt2, ypart, ml);
    hipLaunchKernelGGL(k3c,      dim3(256),     dim3(256), 0, stream, ypart, ml, y, part, mupart);
    hipLaunchKernelGGL(k4b_red,  dim3(65,8),    dim3(256), 0, stream, part, mupart, S);
    hipLaunchKernelGGL(k4c_coef, dim3(256),     dim3(128), 0, stream, S, W_w, W_b, bg, bb, sc, AB);
    hipLaunchKernelGGL(k5_out,   dim3(64,4,4),  dim3(256), 0, stream, Ww_h, y, x, AB, (float*)d_out);
}